// Round 1
// baseline (1092.847 us; speedup 1.0000x reference)
//
#include <hip/hip_runtime.h>
#include <cstdint>
#include <cstddef>

// Problem constants (B=2048, H=4096, K=4)
#define HD   4096
#define BSZ  2048

// GEMM tile config (m97-style): 128x128 block, 4 waves (2x2), BK=64,
// 16x16x32 bf16 MFMA, global_load_lds width-16 staging.
constexpr int BM = 128, BN = 128, BKT = 64;

typedef __bf16 bf16x8 __attribute__((ext_vector_type(8)));
typedef float  f32x4  __attribute__((ext_vector_type(4)));

__device__ __forceinline__ unsigned short f2bf(float f) {
  unsigned u = __float_as_uint(f);
  u += 0x7fffu + ((u >> 16) & 1u);   // RNE
  return (unsigned short)(u >> 16);
}
__device__ __forceinline__ float bf2f(unsigned short s) {
  return __uint_as_float(((unsigned)s) << 16);
}

#define AS1(p) ((__attribute__((address_space(1))) void*)(void*)(p))
#define AS3(p) ((__attribute__((address_space(3))) void*)(p))

// ---------------------------------------------------------------- converts
__global__ void cvt_f32_to_bf16(const float4* __restrict__ src,
                                ushort4* __restrict__ dst, int n4) {
  int i = blockIdx.x * blockDim.x + threadIdx.x;
  if (i >= n4) return;
  float4 v = src[i];
  ushort4 o;
  o.x = f2bf(v.x); o.y = f2bf(v.y); o.z = f2bf(v.z); o.w = f2bf(v.w);
  dst[i] = o;
}

// ---------------------------------------------------------------- GEMM
// C[m][n] = sum_k A[m][k] * Bw[n][k]; A: MxK bf16 row-major, Bw: NxK bf16
// row-major. MODE 0: plain f32 store to outf (ld N).
// MODE 1 (GEMM1): n <  HD -> gate_bf[m][n]   = bf16(gelu_exact(v))
//                 n >= HD -> xrec[m][n-HD]   = v (f32)
template <int MODE>
__global__ __launch_bounds__(256) void gemm_bt(
    const unsigned short* __restrict__ A, const unsigned short* __restrict__ Bw,
    float* __restrict__ outf, unsigned short* __restrict__ gate_bf,
    float* __restrict__ xrec, int M, int N, int K) {
  __shared__ unsigned short smA[BM * BKT];
  __shared__ unsigned short smB[BN * BKT];
  const int tid  = threadIdx.x;
  const int wid  = tid >> 6;
  const int lane = tid & 63;
  const int wm = wid >> 1, wn = wid & 1;        // 2x2 waves over 128x128
  const int l16 = lane & 15, q = lane >> 4;
  const int bx = blockIdx.x, by = blockIdx.y;
  const int srow = tid >> 3;                    // staging row within 32-row round
  const int scol = (tid & 7) * 8;               // staging k-offset (elements)
  const unsigned short* Ab = A + (size_t)(by * BM) * K + scol;
  const unsigned short* Bb = Bw + (size_t)(bx * BN) * K + scol;
  const int ldsbase = (wid * 8) * BKT;          // wave-uniform LDS base (elems)
  f32x4 acc[4][4] = {};

  for (int kt = 0; kt < K; kt += BKT) {
#pragma unroll
    for (int i = 0; i < 4; ++i) {               // 4 rounds x 32 rows, A and B
      __builtin_amdgcn_global_load_lds(AS1(Ab + (size_t)(i * 32 + srow) * K + kt),
                                       AS3(smA + i * 32 * BKT + ldsbase), 16, 0, 0);
      __builtin_amdgcn_global_load_lds(AS1(Bb + (size_t)(i * 32 + srow) * K + kt),
                                       AS3(smB + i * 32 * BKT + ldsbase), 16, 0, 0);
    }
    __syncthreads();
#pragma unroll
    for (int kk = 0; kk < BKT; kk += 32) {
      bf16x8 af[4], bfr[4];
#pragma unroll
      for (int i = 0; i < 4; ++i)
        af[i]  = *(const bf16x8*)(smA + (wm * 64 + i * 16 + l16) * BKT + kk + q * 8);
#pragma unroll
      for (int j = 0; j < 4; ++j)
        bfr[j] = *(const bf16x8*)(smB + (wn * 64 + j * 16 + l16) * BKT + kk + q * 8);
#pragma unroll
      for (int i = 0; i < 4; ++i)
#pragma unroll
        for (int j = 0; j < 4; ++j)
          acc[i][j] = __builtin_amdgcn_mfma_f32_16x16x32_bf16(af[i], bfr[j], acc[i][j], 0, 0, 0);
    }
    __syncthreads();
  }

  // epilogue: C/D layout col = lane&15, row = q*4 + reg (m89-verified)
  const int gm0 = by * BM + wm * 64 + q * 4;
  const int gn0 = bx * BN + wn * 64 + l16;
#pragma unroll
  for (int i = 0; i < 4; ++i) {
#pragma unroll
    for (int j = 0; j < 4; ++j) {
      const int n = gn0 + j * 16;
#pragma unroll
      for (int r = 0; r < 4; ++r) {
        const int m = gm0 + i * 16 + r;
        float v = acc[i][j][r];
        if (MODE == 0) {
          outf[(size_t)m * N + n] = v;
        } else {
          if (n < HD) {  // block-uniform branch (H multiple of 128)
            float g = 0.5f * v * (1.0f + erff(v * 0.70710678118654752f));
            gate_bf[(size_t)m * HD + n] = f2bf(g);
          } else {
            xrec[(size_t)m * HD + (n - HD)] = v;
          }
        }
      }
    }
  }
}

// ---------------------------------------------------------------- conv fuse
// x_conv = cs0*w0 + cs1*w1 + cs2*w2 + x_recur*w3 + b ; also writes
// new_conv_state = [cs1, cs2, x_recur] and bf16(x_conv).
// NOTE: xr and xc_out alias (in-place) -> no __restrict__ on them.
__global__ void conv_fuse(const float* __restrict__ cs, const float* xr,
                          const float4* __restrict__ cw, const float* __restrict__ cb,
                          float* __restrict__ ncs, float* xc_out,
                          unsigned short* __restrict__ xc_bf) {
  int t = blockIdx.x * 256 + threadIdx.x;       // t < BSZ*HD
  int h = t & (HD - 1);
  float c0 = cs[3 * t + 0];
  float c1 = cs[3 * t + 1];
  float c2 = cs[3 * t + 2];
  float xv = xr[t];
  float4 w = cw[h];
  float v = fmaf(c0, w.x, fmaf(c1, w.y, fmaf(c2, w.z, fmaf(xv, w.w, cb[h]))));
  ncs[3 * t + 0] = c1;
  ncs[3 * t + 1] = c2;
  ncs[3 * t + 2] = xv;
  xc_out[t] = v;
  xc_bf[t] = f2bf(v);
}

// ---------------------------------------------------------------- rglru fuse
__global__ void rglru_fuse(const float* __restrict__ gates, const float* __restrict__ av,
                           const float* __restrict__ rs, const float* __restrict__ xc,
                           const unsigned short* __restrict__ gbf,
                           float* __restrict__ nrs, unsigned short* __restrict__ gated) {
  int t = blockIdx.x * 256 + threadIdx.x;       // t < BSZ*HD
  int h = t & (HD - 1);
  int b = t >> 12;
  float gi = gates[(size_t)b * (2 * HD) + h];
  float gr = gates[(size_t)b * (2 * HD) + HD + h];
  float it = 1.0f / (1.0f + expf(-gi));
  float rt = 1.0f / (1.0f + expf(-gr));
  float at = expf(8.0f * rt * logf(av[h]));
  float mult = sqrtf(fmaxf(0.0f, 1.0f - at * at));
  float x = xc[t];
  float nv = fmaf(rs[t], at, mult * (it * x));
  nrs[t] = nv;
  gated[t] = f2bf(bf2f(gbf[t]) * nv);
}

// ---------------------------------------------------------------- launch
extern "C" void kernel_launch(void* const* d_in, const int* in_sizes, int n_in,
                              void* d_out, int out_size, void* d_ws, size_t ws_size,
                              hipStream_t stream) {
  const float* x  = (const float*)d_in[0];
  const float* cs = (const float*)d_in[1];
  const float* rs = (const float*)d_in[2];
  const float* wf = (const float*)d_in[3];
  const float* cw = (const float*)d_in[4];
  const float* cb = (const float*)d_in[5];
  const float* wg = (const float*)d_in[6];
  const float* av = (const float*)d_in[7];
  const float* wo = (const float*)d_in[8];

  float* out = (float*)d_out;                        // (B,H)
  float* ncs = out + (size_t)BSZ * HD;               // (B,H,3)
  float* nrs = out + (size_t)BSZ * HD * 4;           // (B,H)

  // ws layout (240 MiB):
  // [0,16M)    x_bf            -> reused as gated_bf after GEMM1
  // [16M,80M)  wf_bf           -> reused as gates f32 after GEMM1
  // [80M,144M) wg_bf
  // [144M,176M)wo_bf
  // [176M,192M)gate_bf
  // [192M,224M)x_recur -> x_conv f32 (in-place)
  // [224M,240M)x_conv bf16
  char* ws = (char*)d_ws;
  unsigned short* x_bf   = (unsigned short*)(ws);
  unsigned short* wf_bf  = (unsigned short*)(ws + (size_t)(16u)  * 1048576u);
  unsigned short* wg_bf  = (unsigned short*)(ws + (size_t)(80u)  * 1048576u);
  unsigned short* wo_bf  = (unsigned short*)(ws + (size_t)(144u) * 1048576u);
  unsigned short* gatebf = (unsigned short*)(ws + (size_t)(176u) * 1048576u);
  float*          xrc    = (float*)         (ws + (size_t)(192u) * 1048576u);
  unsigned short* xc_bf  = (unsigned short*)(ws + (size_t)(224u) * 1048576u);
  float*          gates  = (float*)wf_bf;            // alias: wf_bf dead after GEMM1
  unsigned short* gated  = x_bf;                     // alias: x_bf dead after GEMM1

  // 1) bf16 conversions
  cvt_f32_to_bf16<<<(BSZ * HD / 4) / 256, 256, 0, stream>>>((const float4*)x,  (ushort4*)x_bf,  BSZ * HD / 4);
  cvt_f32_to_bf16<<<(2 * HD * HD / 4) / 256, 256, 0, stream>>>((const float4*)wf, (ushort4*)wf_bf, 2 * HD * HD / 4);
  cvt_f32_to_bf16<<<(2 * HD * HD / 4) / 256, 256, 0, stream>>>((const float4*)wg, (ushort4*)wg_bf, 2 * HD * HD / 4);
  cvt_f32_to_bf16<<<(HD * HD / 4) / 256, 256, 0, stream>>>((const float4*)wo, (ushort4*)wo_bf, HD * HD / 4);

  dim3 blk(256);
  // 2) fused = x @ w_fused^T, split epilogue (gelu->gate_bf | x_recur f32)
  dim3 g1(2 * HD / BN, BSZ / BM);
  gemm_bt<1><<<g1, blk, 0, stream>>>(x_bf, wf_bf, nullptr, gatebf, xrc, BSZ, 2 * HD, HD);
  // 3) conv + state shift
  conv_fuse<<<(BSZ * HD) / 256, 256, 0, stream>>>(cs, xrc, (const float4*)cw, cb, ncs, xrc, xc_bf);
  // 4) gates = x_conv @ w_gates^T
  gemm_bt<0><<<g1, blk, 0, stream>>>(xc_bf, wg_bf, gates, nullptr, nullptr, BSZ, 2 * HD, HD);
  // 5) rglru recurrence + gated = gate * new_state
  rglru_fuse<<<(BSZ * HD) / 256, 256, 0, stream>>>(gates, av, rs, xrc, gatebf, nrs, gated);
  // 6) out = gated @ w_out^T
  dim3 g3(HD / BN, BSZ / BM);
  gemm_bt<0><<<g3, blk, 0, stream>>>(gated, wo_bf, out, nullptr, nullptr, BSZ, HD, HD);
}

// Round 2
// 1001.708 us; speedup vs baseline: 1.0910x; 1.0910x over previous
//
#include <hip/hip_runtime.h>
#include <cstdint>
#include <cstddef>

// Problem constants (B=2048, H=4096, K=4)
#define HD   4096
#define BSZ  2048

// GEMM tile config (m97-style): 128x128 block, 4 waves (2x2), BK=64,
// 16x16x32 bf16 MFMA, global_load_lds width-16 staging.
// LDS k-chunk XOR swizzle (chunk ^= row&7) to kill the 128B-row-stride
// bank conflicts (R1: SQ_LDS_BANK_CONFLICT 5e7 = ~33% of cycles).
constexpr int BM = 128, BN = 128, BKT = 64;

typedef __bf16 bf16x8 __attribute__((ext_vector_type(8)));
typedef float  f32x4  __attribute__((ext_vector_type(4)));

__device__ __forceinline__ unsigned short f2bf(float f) {
  unsigned u = __float_as_uint(f);
  u += 0x7fffu + ((u >> 16) & 1u);   // RNE
  return (unsigned short)(u >> 16);
}
__device__ __forceinline__ float bf2f(unsigned short s) {
  return __uint_as_float(((unsigned)s) << 16);
}

#define AS1(p) ((__attribute__((address_space(1))) void*)(void*)(p))
#define AS3(p) ((__attribute__((address_space(3))) void*)(p))

// ---------------------------------------------------------------- converts
__global__ void cvt_f32_to_bf16(const float4* __restrict__ src,
                                ushort4* __restrict__ dst, int n4) {
  int i = blockIdx.x * blockDim.x + threadIdx.x;
  if (i >= n4) return;
  float4 v = src[i];
  ushort4 o;
  o.x = f2bf(v.x); o.y = f2bf(v.y); o.z = f2bf(v.z); o.w = f2bf(v.w);
  dst[i] = o;
}

// ---------------------------------------------------------------- GEMM
// C[m][n] = sum_k A[m][k] * Bw[n][k]; A: MxK bf16 row-major, Bw: NxK bf16
// row-major.
// MODE 0: plain f32 store to outf (ld N).
// MODE 1 (GEMM1): n <  HD -> gate_bf[m][n] = bf16(gelu_exact(v))
//                 n >= HD -> xrec[m][n-HD] = v (f32)
// MODE 2 (GEMM2): gate_bf[m][n] = bf16(sigmoid(v))   (ld N = 2H)
template <int MODE>
__global__ __launch_bounds__(256) void gemm_bt(
    const unsigned short* __restrict__ A, const unsigned short* __restrict__ Bw,
    float* __restrict__ outf, unsigned short* __restrict__ gate_bf,
    float* __restrict__ xrec, int M, int N, int K) {
  __shared__ unsigned short smA[BM * BKT];
  __shared__ unsigned short smB[BN * BKT];
  const int tid  = threadIdx.x;
  const int wid  = tid >> 6;
  const int lane = tid & 63;
  const int wm = wid >> 1, wn = wid & 1;        // 2x2 waves over 128x128
  const int l16 = lane & 15, q = lane >> 4;
  const int bx = blockIdx.x, by = blockIdx.y;
  const int srow = tid >> 3;                    // staging row within 32-row round
  // Swizzled source k-chunk: lane's fixed LDS slot is chunk (tid&7) at row
  // srow; under phys = logical ^ (row&7) it must FETCH logical chunk
  // (tid&7) ^ (srow&7). (srow&7 == (lane>>3) since wid*8 ≡ 0 mod 8.)
  const int scol = (((tid & 7) ^ ((tid >> 3) & 7)) * 8);
  const unsigned short* Ab = A + (size_t)(by * BM) * K + scol;
  const unsigned short* Bb = Bw + (size_t)(bx * BN) * K + scol;
  const int ldsbase = (wid * 8) * BKT;          // wave-uniform LDS base (elems)
  f32x4 acc[4][4] = {};

  for (int kt = 0; kt < K; kt += BKT) {
#pragma unroll
    for (int i = 0; i < 4; ++i) {               // 4 rounds x 32 rows, A and B
      __builtin_amdgcn_global_load_lds(AS1(Ab + (size_t)(i * 32 + srow) * K + kt),
                                       AS3(smA + i * 32 * BKT + ldsbase), 16, 0, 0);
      __builtin_amdgcn_global_load_lds(AS1(Bb + (size_t)(i * 32 + srow) * K + kt),
                                       AS3(smB + i * 32 * BKT + ldsbase), 16, 0, 0);
    }
    __syncthreads();
#pragma unroll
    for (int kk = 0; kk < BKT; kk += 32) {
      bf16x8 af[4], bfr[4];
#pragma unroll
      for (int i = 0; i < 4; ++i) {
        const int ar = wm * 64 + i * 16 + l16;
        af[i]  = *(const bf16x8*)(smA + ar * BKT + ((((kk >> 3) + q) ^ (ar & 7)) * 8));
      }
#pragma unroll
      for (int j = 0; j < 4; ++j) {
        const int br = wn * 64 + j * 16 + l16;
        bfr[j] = *(const bf16x8*)(smB + br * BKT + ((((kk >> 3) + q) ^ (br & 7)) * 8));
      }
#pragma unroll
      for (int i = 0; i < 4; ++i)
#pragma unroll
        for (int j = 0; j < 4; ++j)
          acc[i][j] = __builtin_amdgcn_mfma_f32_16x16x32_bf16(af[i], bfr[j], acc[i][j], 0, 0, 0);
    }
    __syncthreads();
  }

  // epilogue: C/D layout col = lane&15, row = q*4 + reg (m89-verified)
  const int gm0 = by * BM + wm * 64 + q * 4;
  const int gn0 = bx * BN + wn * 64 + l16;
#pragma unroll
  for (int i = 0; i < 4; ++i) {
#pragma unroll
    for (int j = 0; j < 4; ++j) {
      const int n = gn0 + j * 16;
#pragma unroll
      for (int r = 0; r < 4; ++r) {
        const int m = gm0 + i * 16 + r;
        float v = acc[i][j][r];
        if (MODE == 0) {
          outf[(size_t)m * N + n] = v;
        } else if (MODE == 2) {
          float s = 1.0f / (1.0f + expf(-v));
          gate_bf[(size_t)m * N + n] = f2bf(s);
        } else {
          if (n < HD) {  // block-uniform branch (H multiple of 128)
            float g = 0.5f * v * (1.0f + erff(v * 0.70710678118654752f));
            gate_bf[(size_t)m * HD + n] = f2bf(g);
          } else {
            xrec[(size_t)m * HD + (n - HD)] = v;
          }
        }
      }
    }
  }
}

// ---------------------------------------------------------------- conv fuse
// x_conv = cs0*w0 + cs1*w1 + cs2*w2 + x_recur*w3 + b ; also writes
// new_conv_state = [cs1, cs2, x_recur] and bf16(x_conv).
// NOTE: xr and xc_out alias (in-place) -> no __restrict__ on them.
__global__ void conv_fuse(const float* __restrict__ cs, const float* xr,
                          const float4* __restrict__ cw, const float* __restrict__ cb,
                          float* __restrict__ ncs, float* xc_out,
                          unsigned short* __restrict__ xc_bf) {
  int t = blockIdx.x * 256 + threadIdx.x;       // t < BSZ*HD
  int h = t & (HD - 1);
  float c0 = cs[3 * t + 0];
  float c1 = cs[3 * t + 1];
  float c2 = cs[3 * t + 2];
  float xv = xr[t];
  float4 w = cw[h];
  float v = fmaf(c0, w.x, fmaf(c1, w.y, fmaf(c2, w.z, fmaf(xv, w.w, cb[h]))));
  ncs[3 * t + 0] = c1;
  ncs[3 * t + 1] = c2;
  ncs[3 * t + 2] = xv;
  xc_out[t] = v;
  xc_bf[t] = f2bf(v);
}

// ---------------------------------------------------------------- rglru fuse
// gates_bf holds bf16 sigmoid outputs: i_t at [b][h], r_t at [b][H+h].
__global__ void rglru_fuse(const unsigned short* __restrict__ gates_bf,
                           const float* __restrict__ av,
                           const float* __restrict__ rs, const float* __restrict__ xc,
                           const unsigned short* __restrict__ gbf,
                           float* __restrict__ nrs, unsigned short* __restrict__ gated) {
  int t = blockIdx.x * 256 + threadIdx.x;       // t < BSZ*HD
  int h = t & (HD - 1);
  int b = t >> 12;
  float it = bf2f(gates_bf[(size_t)b * (2 * HD) + h]);
  float rt = bf2f(gates_bf[(size_t)b * (2 * HD) + HD + h]);
  float at = expf(8.0f * rt * logf(av[h]));
  float mult = sqrtf(fmaxf(0.0f, 1.0f - at * at));
  float x = xc[t];
  float nv = fmaf(rs[t], at, mult * (it * x));
  nrs[t] = nv;
  gated[t] = f2bf(bf2f(gbf[t]) * nv);
}

// ---------------------------------------------------------------- launch
extern "C" void kernel_launch(void* const* d_in, const int* in_sizes, int n_in,
                              void* d_out, int out_size, void* d_ws, size_t ws_size,
                              hipStream_t stream) {
  const float* x  = (const float*)d_in[0];
  const float* cs = (const float*)d_in[1];
  const float* rs = (const float*)d_in[2];
  const float* wf = (const float*)d_in[3];
  const float* cw = (const float*)d_in[4];
  const float* cb = (const float*)d_in[5];
  const float* wg = (const float*)d_in[6];
  const float* av = (const float*)d_in[7];
  const float* wo = (const float*)d_in[8];

  float* out = (float*)d_out;                        // (B,H)
  float* ncs = out + (size_t)BSZ * HD;               // (B,H,3)
  float* nrs = out + (size_t)BSZ * HD * 4;           // (B,H)

  // ws layout (240 MiB):
  // [0,16M)    x_bf            -> reused as gated_bf after GEMM1
  // [16M,80M)  wf_bf           -> reused as gates_bf (bf16 sigmoids) after GEMM1
  // [80M,144M) wg_bf
  // [144M,176M)wo_bf
  // [176M,192M)gate_bf
  // [192M,224M)x_recur -> x_conv f32 (in-place)
  // [224M,240M)x_conv bf16
  char* ws = (char*)d_ws;
  unsigned short* x_bf   = (unsigned short*)(ws);
  unsigned short* wf_bf  = (unsigned short*)(ws + (size_t)(16u)  * 1048576u);
  unsigned short* wg_bf  = (unsigned short*)(ws + (size_t)(80u)  * 1048576u);
  unsigned short* wo_bf  = (unsigned short*)(ws + (size_t)(144u) * 1048576u);
  unsigned short* gatebf = (unsigned short*)(ws + (size_t)(176u) * 1048576u);
  float*          xrc    = (float*)         (ws + (size_t)(192u) * 1048576u);
  unsigned short* xc_bf  = (unsigned short*)(ws + (size_t)(224u) * 1048576u);
  unsigned short* gates_bf = wf_bf;                  // alias: wf_bf dead after GEMM1
  unsigned short* gated    = x_bf;                   // alias: x_bf dead after GEMM1

  // 1) bf16 conversions
  cvt_f32_to_bf16<<<(BSZ * HD / 4) / 256, 256, 0, stream>>>((const float4*)x,  (ushort4*)x_bf,  BSZ * HD / 4);
  cvt_f32_to_bf16<<<(2 * HD * HD / 4) / 256, 256, 0, stream>>>((const float4*)wf, (ushort4*)wf_bf, 2 * HD * HD / 4);
  cvt_f32_to_bf16<<<(2 * HD * HD / 4) / 256, 256, 0, stream>>>((const float4*)wg, (ushort4*)wg_bf, 2 * HD * HD / 4);
  cvt_f32_to_bf16<<<(HD * HD / 4) / 256, 256, 0, stream>>>((const float4*)wo, (ushort4*)wo_bf, HD * HD / 4);

  dim3 blk(256);
  // 2) fused = x @ w_fused^T, split epilogue (gelu->gate_bf | x_recur f32)
  dim3 g1(2 * HD / BN, BSZ / BM);
  gemm_bt<1><<<g1, blk, 0, stream>>>(x_bf, wf_bf, nullptr, gatebf, xrc, BSZ, 2 * HD, HD);
  // 3) conv + state shift
  conv_fuse<<<(BSZ * HD) / 256, 256, 0, stream>>>(cs, xrc, (const float4*)cw, cb, ncs, xrc, xc_bf);
  // 4) gates = sigmoid(x_conv @ w_gates^T) -> bf16
  gemm_bt<2><<<g1, blk, 0, stream>>>(xc_bf, wg_bf, nullptr, gates_bf, nullptr, BSZ, 2 * HD, HD);
  // 5) rglru recurrence + gated = gate * new_state
  rglru_fuse<<<(BSZ * HD) / 256, 256, 0, stream>>>(gates_bf, av, rs, xrc, gatebf, nrs, gated);
  // 6) out = gated @ w_out^T
  dim3 g3(HD / BN, BSZ / BM);
  gemm_bt<0><<<g3, blk, 0, stream>>>(gated, wo_bf, out, nullptr, nullptr, BSZ, HD, HD);
}